// Round 10
// baseline (28.933 us; speedup 1.0000x reference)
//
#include <hip/hip_runtime.h>

#define BATCH 384
#define DIM   1024
#define MARGIN_F 0.5f
#define EPS_F 1e-16f
#define N2 (BATCH * BATCH)

// ---------------------------------------------------------------------------
// Kernel 1: split-K partial gram, UPPER-TRIANGLE 32x32 tiles (R7 verbatim).
// Block (0,0,0) additionally zeroes the counter + 3 double accumulators;
// end-of-kernel release makes these visible to kernel 2 (proven in R9).
// ---------------------------------------------------------------------------
__global__ __launch_bounds__(256) void dist_kernel(const float* __restrict__ E,
                                                   float* __restrict__ dpart,
                                                   float* __restrict__ ddiag,
                                                   unsigned* __restrict__ ctr,
                                                   double* __restrict__ acc) {
    const int bx = blockIdx.x, by = blockIdx.y;

    if (bx == 0 && by == 0 && blockIdx.z == 0 && threadIdx.x == 0) {
        *ctr = 0u;
        acc[0] = 0.0;   // sum      (cacheline 0)
        acc[8] = 0.0;   // npos     (cacheline 1)
        acc[16] = 0.0;  // nvalid   (cacheline 2)
    }

    if (bx < by) return;   // triangle: only cb >= rb tiles do work

    __shared__ float As[32][36];
    __shared__ float Bs[32][36];

    const int tx = threadIdx.x & 15;
    const int ty = threadIdx.x >> 4;
    const int rb = by * 32;
    const int cb = bx * 32;
    const int kb = blockIdx.z * (DIM / 8);
    const int kslice = DIM / 8;

    float acc00 = 0.f, acc01 = 0.f, acc10 = 0.f, acc11 = 0.f;

    const int lr = threadIdx.x >> 3;        // 0..31 row within tile
    const int lc = (threadIdx.x & 7) * 4;   // 0,4,...,28

    for (int k0 = 0; k0 < kslice; k0 += 32) {
        *(float4*)&As[lr][lc] = *(const float4*)&E[(size_t)(rb + lr) * DIM + kb + k0 + lc];
        *(float4*)&Bs[lr][lc] = *(const float4*)&E[(size_t)(cb + lr) * DIM + kb + k0 + lc];
        __syncthreads();

#pragma unroll
        for (int k = 0; k < 32; k += 4) {
            float4 a0 = *(const float4*)&As[ty][k];
            float4 a1 = *(const float4*)&As[ty + 16][k];
            float4 b0 = *(const float4*)&Bs[tx][k];
            float4 b1 = *(const float4*)&Bs[tx + 16][k];
            acc00 += a0.x * b0.x + a0.y * b0.y + a0.z * b0.z + a0.w * b0.w;
            acc01 += a0.x * b1.x + a0.y * b1.y + a0.z * b1.z + a0.w * b1.w;
            acc10 += a1.x * b0.x + a1.y * b0.y + a1.z * b0.z + a1.w * b0.w;
            acc11 += a1.x * b1.x + a1.y * b1.y + a1.z * b1.z + a1.w * b1.w;
        }
        __syncthreads();
    }

    float* dst = dpart + (size_t)blockIdx.z * N2;
    const int r0 = rb + ty, r1 = rb + ty + 16;
    const int c0 = cb + tx, c1 = cb + tx + 16;
    dst[(size_t)r0 * BATCH + c0] = acc00;
    dst[(size_t)r0 * BATCH + c1] = acc01;
    dst[(size_t)r1 * BATCH + c0] = acc10;
    dst[(size_t)r1 * BATCH + c1] = acc11;

    if (bx != by) {   // mirror store (transposed); bit-identical values
        dst[(size_t)c0 * BATCH + r0] = acc00;
        dst[(size_t)c1 * BATCH + r0] = acc01;
        dst[(size_t)c0 * BATCH + r1] = acc10;
        dst[(size_t)c1 * BATCH + r1] = acc11;
    }

    if (bx == by && tx == ty) {   // compact diagonal partials
        ddiag[blockIdx.z * BATCH + r0] = acc00;
        ddiag[blockIdx.z * BATCH + r1] = acc11;
    }
}

// ---------------------------------------------------------------------------
// Kernel 2: per-anchor triplet reduction (R7 verbatim) + fence-free fused
// finalize. All cross-block data flows through device atomics (coherent at
// L2 point); atomicAdd return values are consumed to force completion order
// before the counter bump, so NO __threadfence / wbl2 is ever emitted.
// ---------------------------------------------------------------------------
__global__ __launch_bounds__(256) void triplet_kernel(const float* __restrict__ dpart,
                                                      const float* __restrict__ ddiag,
                                                      const int* __restrict__ labels,
                                                      double* __restrict__ acc,
                                                      unsigned* __restrict__ ctr,
                                                      float* __restrict__ out) {
    __shared__ float drow[BATCH];
    __shared__ int   lab[BATCH];
    __shared__ int   plist[BATCH];
    __shared__ int   npos_s;
    __shared__ float ssum[4];
    __shared__ int   spos[4];
    __shared__ int   sval[4];
    __shared__ int   lastFlag;

    const int t = threadIdx.x;
    const int a = blockIdx.x;

    float da = 0.f;
#pragma unroll
    for (int z = 0; z < 8; ++z) da += ddiag[z * BATCH + a];

    for (int i = t; i < BATCH; i += 256) {
        float row = 0.f, di = 0.f;
#pragma unroll
        for (int z = 0; z < 8; ++z) {
            row += dpart[(size_t)z * N2 + (size_t)a * BATCH + i];
            di  += ddiag[z * BATCH + i];
        }
        const float s = da + di - 2.f * row;   // exactly 0.0 at i==a
        drow[i] = s > 0.f ? sqrtf(s) : 0.f;
        lab[i]  = labels[i];
    }
    __syncthreads();

    const int la = lab[a];

    // deterministic positives-list build on wave 0
    if (t < 64) {
        int cnt = 0;
#pragma unroll
        for (int c = 0; c < BATCH; c += 64) {
            const int i = c + t;
            const bool f = (lab[i] == la) && (i != a);
            const unsigned long long m = __ballot(f);
            if (f) {
                const int off = __popcll(m & ((1ull << t) - 1ull));
                plist[cnt + off] = i;
            }
            cnt += __popcll(m);
        }
        if (t == 0) npos_s = cnt;
    }
    __syncthreads();

    const int npos = npos_s;
    float sum = 0.f;
    int   pos = 0, valid = 0;

    for (int n = t; n < BATCH; n += 256) {
        if (lab[n] != la) {
            const float dan = drow[n];
            valid += npos;
            for (int q = 0; q < npos; ++q) {
                float tl = drow[plist[q]] - dan + MARGIN_F;
                if (tl > EPS_F) { sum += tl; ++pos; }
            }
        }
    }

#pragma unroll
    for (int off = 32; off > 0; off >>= 1) {
        sum   += __shfl_down(sum, off);
        pos   += __shfl_down(pos, off);
        valid += __shfl_down(valid, off);
    }
    const int wave = t >> 6, lane = t & 63;
    if (lane == 0) { ssum[wave] = sum; spos[wave] = pos; sval[wave] = valid; }
    __syncthreads();

    if (t == 0) {
        float s = 0.f; int p2 = 0, v = 0;
#pragma unroll
        for (int w = 0; w < 4; ++w) { s += ssum[w]; p2 += spos[w]; v += sval[w]; }

        // accumulate via device atomics (coherence point), no fences
        double o0 = atomicAdd(&acc[0],  (double)s);
        double o1 = atomicAdd(&acc[8],  (double)p2);   // integer-valued: exact
        double o2 = atomicAdd(&acc[16], (double)v);    // integer-valued: exact
        // consume returns: forces vmcnt wait so acc-adds complete before ctr add
        asm volatile("" :: "v"(o0), "v"(o1), "v"(o2));
        const unsigned old = atomicAdd(ctr, 1u);
        lastFlag = (old == (unsigned)(BATCH - 1));
    }
    __syncthreads();

    // last block, thread 0: coherent read-back via atomic RMW(+0), divide, store
    if (lastFlag && t == 0) {
        double s = atomicAdd(&acc[0],  0.0);
        double p = atomicAdd(&acc[8],  0.0);
        double v = atomicAdd(&acc[16], 0.0);
        out[0] = (float)(s / (p + 1e-16));
        out[1] = (float)p;
        out[2] = (float)v;
    }
}

extern "C" void kernel_launch(void* const* d_in, const int* in_sizes, int n_in,
                              void* d_out, int out_size, void* d_ws, size_t ws_size,
                              hipStream_t stream) {
    const int*   labels = (const int*)d_in[0];
    const float* E      = (const float*)d_in[1];
    float* out = (float*)d_out;

    // ws: [ctr @0][acc @256: 3 doubles spaced 64B][ddiag @8192: 8*384 f][dpart @24576]
    unsigned* ctr  = (unsigned*)d_ws;
    double*   acc  = (double*)((char*)d_ws + 256);
    float*    ddiag = (float*)((char*)d_ws + 8192);
    float*    dpart = (float*)((char*)d_ws + 24576);

    dim3 grid(BATCH / 32, BATCH / 32, 8);
    dist_kernel<<<grid, 256, 0, stream>>>(E, dpart, ddiag, ctr, acc);
    triplet_kernel<<<BATCH, 256, 0, stream>>>(dpart, ddiag, labels, acc, ctr, out);
}

// Round 11
// 17.609 us; speedup vs baseline: 1.6431x; 1.6431x over previous
//
#include <hip/hip_runtime.h>

#define BATCH 384
#define DIM   1024
#define MARGIN_F 0.5f
#define EPS_F 1e-16f
#define N2 (BATCH * BATCH)
#define SPLIT 8
#define KSLICE 128   // DIM / SPLIT

typedef __attribute__((ext_vector_type(8))) short bf16x8;
typedef __attribute__((ext_vector_type(4))) float f32x4;

__device__ __forceinline__ short f2bf(float f) {   // RNE fp32 -> bf16
    unsigned u = __float_as_uint(f);
    u = (u + 0x7FFFu + ((u >> 16) & 1u)) >> 16;
    return (short)u;
}

// ---------------------------------------------------------------------------
// Kernel 1: split-K partial gram via bf16 MFMA (16x16x32), upper-tri tiles.
// 32x32 tile/block, 4 waves, each wave one 16x16 subtile, K=128 per block.
// Stage: fp32 E rows -> bf16 LDS (one shot). Frag reads: lane l reads 8
// contiguous bf16 at row (l&15), k-group 8*(l>>4)  (A-row / B-col = l&15;
// identical k-map for A and B makes the dot k-permutation-invariant).
// C/D: col = lane&15, row = (lane>>4)*4 + reg  [HW-verified m89].
// Mirror store bit-exact; ddiag partials preserve the exact-0 diagonal.
// ---------------------------------------------------------------------------
__global__ __launch_bounds__(256) void dist_kernel(const float* __restrict__ E,
                                                   float* __restrict__ dpart,
                                                   float* __restrict__ ddiag) {
    const int bx = blockIdx.x, by = blockIdx.y;
    if (bx < by) return;   // triangle

    __shared__ short As[32][132];   // pad 132: 264B row stride, ~2-way banks
    __shared__ short Bs[32][132];

    const int t  = threadIdx.x;
    const int rb = by * 32;
    const int cb = bx * 32;
    const int kb = blockIdx.z * KSLICE;

    // ---- stage: each thread converts 16 floats per array ----
    {
        const int row  = t >> 3;          // 0..31
        const int kc16 = (t & 7) * 16;    // 0,16,...,112
        const float4* pa = (const float4*)&E[(size_t)(rb + row) * DIM + kb + kc16];
        const float4* pb = (const float4*)&E[(size_t)(cb + row) * DIM + kb + kc16];
        bf16x8 a0, a1, b0, b1;
#pragma unroll
        for (int i = 0; i < 2; ++i) {
            float4 va0 = pa[2*i], va1 = pa[2*i+1];
            float4 vb0 = pb[2*i], vb1 = pb[2*i+1];
            bf16x8& ra = i ? a1 : a0;
            bf16x8& rbv = i ? b1 : b0;
            ra[0] = f2bf(va0.x); ra[1] = f2bf(va0.y); ra[2] = f2bf(va0.z); ra[3] = f2bf(va0.w);
            ra[4] = f2bf(va1.x); ra[5] = f2bf(va1.y); ra[6] = f2bf(va1.z); ra[7] = f2bf(va1.w);
            rbv[0] = f2bf(vb0.x); rbv[1] = f2bf(vb0.y); rbv[2] = f2bf(vb0.z); rbv[3] = f2bf(vb0.w);
            rbv[4] = f2bf(vb1.x); rbv[5] = f2bf(vb1.y); rbv[6] = f2bf(vb1.z); rbv[7] = f2bf(vb1.w);
        }
        *(bf16x8*)&As[row][kc16 + 0] = a0;
        *(bf16x8*)&As[row][kc16 + 8] = a1;
        *(bf16x8*)&Bs[row][kc16 + 0] = b0;
        *(bf16x8*)&Bs[row][kc16 + 8] = b1;
    }
    __syncthreads();

    // ---- MFMA: wave wid -> subtile (wr, wc) ----
    const int l   = t & 63;
    const int wid = t >> 6;
    const int wr  = wid >> 1, wc = wid & 1;
    const int fr  = l & 15;    // A row / B col within subtile
    const int fq  = l >> 4;    // k-group (8 bf16 each)

    f32x4 acc = {0.f, 0.f, 0.f, 0.f};
#pragma unroll
    for (int kc = 0; kc < 4; ++kc) {
        bf16x8 a = *(const bf16x8*)&As[wr * 16 + fr][kc * 32 + fq * 8];
        bf16x8 b = *(const bf16x8*)&Bs[wc * 16 + fr][kc * 32 + fq * 8];
        acc = __builtin_amdgcn_mfma_f32_16x16x32_bf16(a, b, acc, 0, 0, 0);
    }

    // ---- store: D[row][col], row = rb+wr*16+fq*4+r, col = cb+wc*16+fr ----
    float* dst = dpart + (size_t)blockIdx.z * N2;
    const int row0 = rb + wr * 16 + fq * 4;
    const int col  = cb + wc * 16 + fr;
#pragma unroll
    for (int r = 0; r < 4; ++r)
        dst[(size_t)(row0 + r) * BATCH + col] = acc[r];

    if (bx != by) {   // mirror store (transposed); bit-identical values
#pragma unroll
        for (int r = 0; r < 4; ++r)
            dst[(size_t)col * BATCH + (row0 + r)] = acc[r];
    }

    // diagonal partials: lanes where local col == local row (fr>>2 == fq)
    if (bx == by && wr == wc && (fr >> 2) == fq) {
        ddiag[blockIdx.z * BATCH + rb + wr * 16 + fr] = acc[fr & 3];
    }
}

// ---------------------------------------------------------------------------
// Kernel 2: per-anchor triplet reduction (VERBATIM round 7).
// ---------------------------------------------------------------------------
__global__ __launch_bounds__(256) void triplet_kernel(const float* __restrict__ dpart,
                                                      const float* __restrict__ ddiag,
                                                      const int* __restrict__ labels,
                                                      float* __restrict__ part) {
    __shared__ float drow[BATCH];
    __shared__ int   lab[BATCH];
    __shared__ int   plist[BATCH];
    __shared__ int   npos_s;
    __shared__ float ssum[4];
    __shared__ int   spos[4];
    __shared__ int   sval[4];

    const int t = threadIdx.x;
    const int a = blockIdx.x;

    float da = 0.f;
#pragma unroll
    for (int z = 0; z < SPLIT; ++z) da += ddiag[z * BATCH + a];

    for (int i = t; i < BATCH; i += 256) {
        float row = 0.f, di = 0.f;
#pragma unroll
        for (int z = 0; z < SPLIT; ++z) {
            row += dpart[(size_t)z * N2 + (size_t)a * BATCH + i];
            di  += ddiag[z * BATCH + i];
        }
        const float s = da + di - 2.f * row;   // exactly 0.0 at i==a
        drow[i] = s > 0.f ? sqrtf(s) : 0.f;
        lab[i]  = labels[i];
    }
    __syncthreads();

    const int la = lab[a];

    if (t < 64) {   // deterministic positives-list build on wave 0
        int cnt = 0;
#pragma unroll
        for (int c = 0; c < BATCH; c += 64) {
            const int i = c + t;
            const bool f = (lab[i] == la) && (i != a);
            const unsigned long long m = __ballot(f);
            if (f) {
                const int off = __popcll(m & ((1ull << t) - 1ull));
                plist[cnt + off] = i;
            }
            cnt += __popcll(m);
        }
        if (t == 0) npos_s = cnt;
    }
    __syncthreads();

    const int npos = npos_s;
    float sum = 0.f;
    int   pos = 0, valid = 0;

    for (int n = t; n < BATCH; n += 256) {
        if (lab[n] != la) {
            const float dan = drow[n];
            valid += npos;
            for (int q = 0; q < npos; ++q) {
                float tl = drow[plist[q]] - dan + MARGIN_F;
                if (tl > EPS_F) { sum += tl; ++pos; }
            }
        }
    }

#pragma unroll
    for (int off = 32; off > 0; off >>= 1) {
        sum   += __shfl_down(sum, off);
        pos   += __shfl_down(pos, off);
        valid += __shfl_down(valid, off);
    }
    const int wave = t >> 6, lane = t & 63;
    if (lane == 0) { ssum[wave] = sum; spos[wave] = pos; sval[wave] = valid; }
    __syncthreads();

    if (t == 0) {
        float s = 0.f; int p2 = 0, v = 0;
#pragma unroll
        for (int w = 0; w < 4; ++w) { s += ssum[w]; p2 += spos[w]; v += sval[w]; }
        part[a]             = s;
        part[BATCH + a]     = (float)p2;
        part[2 * BATCH + a] = (float)v;
    }
}

// ---------------------------------------------------------------------------
// Kernel 3: one-wave finalize (VERBATIM round 7).
// ---------------------------------------------------------------------------
__global__ __launch_bounds__(64) void finalize_kernel(const float* __restrict__ part,
                                                      float* __restrict__ out) {
    const int lane = threadIdx.x;
    double s = 0.0, p = 0.0, v = 0.0;
#pragma unroll
    for (int c = 0; c < BATCH; c += 64) {
        s += (double)part[c + lane];
        p += (double)part[BATCH + c + lane];
        v += (double)part[2 * BATCH + c + lane];
    }
#pragma unroll
    for (int off = 32; off > 0; off >>= 1) {
        s += __shfl_down(s, off);
        p += __shfl_down(p, off);
        v += __shfl_down(v, off);
    }
    if (lane == 0) {
        out[0] = (float)(s / (p + 1e-16));
        out[1] = (float)p;
        out[2] = (float)v;
    }
}

extern "C" void kernel_launch(void* const* d_in, const int* in_sizes, int n_in,
                              void* d_out, int out_size, void* d_ws, size_t ws_size,
                              hipStream_t stream) {
    const int*   labels = (const int*)d_in[0];
    const float* E      = (const float*)d_in[1];
    float* out = (float*)d_out;

    // ws layout: [part @0: 3*384 f][ddiag @8192: 8*384 f][dpart @24576: 8*N2 f]
    float* part  = (float*)d_ws;
    float* ddiag = (float*)((char*)d_ws + 8192);
    float* dpart = (float*)((char*)d_ws + 24576);

    dim3 grid(BATCH / 32, BATCH / 32, SPLIT);
    dist_kernel<<<grid, 256, 0, stream>>>(E, dpart, ddiag);
    triplet_kernel<<<BATCH, 256, 0, stream>>>(dpart, ddiag, labels, part);
    finalize_kernel<<<1, 64, 0, stream>>>(part, out);
}

// Round 12
// 16.098 us; speedup vs baseline: 1.7973x; 1.0939x over previous
//
#include <hip/hip_runtime.h>

#define BATCH 384
#define DIM   1024
#define MARGIN_F 0.5f
#define EPS_F 1e-16f
#define N2 (BATCH * BATCH)
#define NTILE 12                  // 384/32
#define NUT   78                  // upper-triangle tiles
#define SPLIT 4                   // K slices
#define KSLICE 256                // DIM / SPLIT
#define DIST_BLKS (NUT * SPLIT)   // 312

typedef __attribute__((ext_vector_type(8))) short bf16x8;
typedef __attribute__((ext_vector_type(4))) float f32x4;

__device__ __forceinline__ short f2bf(float f) {   // RNE fp32 -> bf16
    unsigned u = __float_as_uint(f);
    u = (u + 0x7FFFu + ((u >> 16) & 1u)) >> 16;
    return (short)u;
}

// ---------------------------------------------------------------------------
// Kernel 1: split-K partial gram via bf16 MFMA (16x16x32), upper-tri tiles,
// linear 312-block grid (mapping proven R9), KSLICE=256 (2 stage passes,
// 8 MFMAs/wave). Mirror store bit-exact; ddiag partials -> exact-0 diagonal.
// ---------------------------------------------------------------------------
__global__ __launch_bounds__(256) void dist_kernel(const float* __restrict__ E,
                                                   float* __restrict__ dpart,
                                                   float* __restrict__ ddiag) {
    __shared__ short As[32][260];   // 520B row stride: rows offset 2 banks
    __shared__ short Bs[32][260];

    const int bid = blockIdx.x;
    const int z   = bid / NUT;
    int tt        = bid % NUT;
    int by = 0;
    while (tt >= NTILE - by) { tt -= NTILE - by; ++by; }
    const int bx = by + tt;          // bx >= by

    const int t  = threadIdx.x;
    const int rb = by * 32;
    const int cb = bx * 32;
    const int kb = z * KSLICE;

    // ---- stage: 2 passes of 128 k; each thread converts 16 floats/array/pass
    {
        const int row  = t >> 3;          // 0..31
        const int kc16 = (t & 7) * 16;    // 0,16,...,112
#pragma unroll
        for (int p = 0; p < 2; ++p) {
            const int ko = p * 128 + kc16;
            const float4* pa = (const float4*)&E[(size_t)(rb + row) * DIM + kb + ko];
            const float4* pb = (const float4*)&E[(size_t)(cb + row) * DIM + kb + ko];
            bf16x8 a0, a1, b0, b1;
#pragma unroll
            for (int i = 0; i < 2; ++i) {
                float4 va0 = pa[2*i], va1 = pa[2*i+1];
                float4 vb0 = pb[2*i], vb1 = pb[2*i+1];
                bf16x8& ra  = i ? a1 : a0;
                bf16x8& rbv = i ? b1 : b0;
                ra[0] = f2bf(va0.x); ra[1] = f2bf(va0.y); ra[2] = f2bf(va0.z); ra[3] = f2bf(va0.w);
                ra[4] = f2bf(va1.x); ra[5] = f2bf(va1.y); ra[6] = f2bf(va1.z); ra[7] = f2bf(va1.w);
                rbv[0] = f2bf(vb0.x); rbv[1] = f2bf(vb0.y); rbv[2] = f2bf(vb0.z); rbv[3] = f2bf(vb0.w);
                rbv[4] = f2bf(vb1.x); rbv[5] = f2bf(vb1.y); rbv[6] = f2bf(vb1.z); rbv[7] = f2bf(vb1.w);
            }
            *(bf16x8*)&As[row][ko + 0] = a0;
            *(bf16x8*)&As[row][ko + 8] = a1;
            *(bf16x8*)&Bs[row][ko + 0] = b0;
            *(bf16x8*)&Bs[row][ko + 8] = b1;
        }
    }
    __syncthreads();

    // ---- MFMA: wave wid -> 16x16 subtile (wr, wc) ----
    const int l   = t & 63;
    const int wid = t >> 6;
    const int wr  = wid >> 1, wc = wid & 1;
    const int fr  = l & 15;    // A row / B col within subtile
    const int fq  = l >> 4;    // k-group (8 bf16 each)

    f32x4 acc = {0.f, 0.f, 0.f, 0.f};
#pragma unroll
    for (int kc = 0; kc < 8; ++kc) {
        bf16x8 a = *(const bf16x8*)&As[wr * 16 + fr][kc * 32 + fq * 8];
        bf16x8 b = *(const bf16x8*)&Bs[wc * 16 + fr][kc * 32 + fq * 8];
        acc = __builtin_amdgcn_mfma_f32_16x16x32_bf16(a, b, acc, 0, 0, 0);
    }

    // ---- store: D[row][col], row = rb+wr*16+fq*4+r, col = cb+wc*16+fr ----
    float* dst = dpart + (size_t)z * N2;
    const int row0 = rb + wr * 16 + fq * 4;
    const int col  = cb + wc * 16 + fr;
#pragma unroll
    for (int r = 0; r < 4; ++r)
        dst[(size_t)(row0 + r) * BATCH + col] = acc[r];

    if (bx != by) {   // mirror store (transposed); bit-identical values
#pragma unroll
        for (int r = 0; r < 4; ++r)
            dst[(size_t)col * BATCH + (row0 + r)] = acc[r];
    }

    // diagonal partials: lanes where local col == local row
    if (bx == by && wr == wc && (fr >> 2) == fq) {
        ddiag[z * BATCH + rb + wr * 16 + fr] = acc[fr & 3];
    }
}

// ---------------------------------------------------------------------------
// Kernel 2: per-anchor triplet reduction. float4 staging (96 threads x
// float4 over i; per-lane z order ascending -> exact-0 diagonal preserved).
// Hinge phase verbatim from R7/R11.
// ---------------------------------------------------------------------------
__global__ __launch_bounds__(256) void triplet_kernel(const float* __restrict__ dpart,
                                                      const float* __restrict__ ddiag,
                                                      const int* __restrict__ labels,
                                                      float* __restrict__ part) {
    __shared__ float drow[BATCH];
    __shared__ int   lab[BATCH];
    __shared__ int   plist[BATCH];
    __shared__ int   npos_s;
    __shared__ float ssum[4];
    __shared__ int   spos[4];
    __shared__ int   sval[4];

    const int t = threadIdx.x;
    const int a = blockIdx.x;

    float da = 0.f;
#pragma unroll
    for (int z = 0; z < SPLIT; ++z) da += ddiag[z * BATCH + a];

    if (t < 96) {                      // 96 x 4 = 384 elements
        const int i4 = t * 4;
        float4 row = {0.f, 0.f, 0.f, 0.f};
        float4 di  = {0.f, 0.f, 0.f, 0.f};
#pragma unroll
        for (int z = 0; z < SPLIT; ++z) {
            float4 r = *(const float4*)&dpart[(size_t)z * N2 + (size_t)a * BATCH + i4];
            float4 d = *(const float4*)&ddiag[z * BATCH + i4];
            row.x += r.x; row.y += r.y; row.z += r.z; row.w += r.w;
            di.x  += d.x; di.y  += d.y; di.z  += d.z; di.w  += d.w;
        }
        float4 s;
        s.x = da + di.x - 2.f * row.x;   // exactly 0.0 at i==a
        s.y = da + di.y - 2.f * row.y;
        s.z = da + di.z - 2.f * row.z;
        s.w = da + di.w - 2.f * row.w;
        float4 dr;
        dr.x = s.x > 0.f ? sqrtf(s.x) : 0.f;
        dr.y = s.y > 0.f ? sqrtf(s.y) : 0.f;
        dr.z = s.z > 0.f ? sqrtf(s.z) : 0.f;
        dr.w = s.w > 0.f ? sqrtf(s.w) : 0.f;
        *(float4*)&drow[i4] = dr;
    }
    for (int i = t; i < BATCH; i += 256) lab[i] = labels[i];
    __syncthreads();

    const int la = lab[a];

    if (t < 64) {   // deterministic positives-list build on wave 0
        int cnt = 0;
#pragma unroll
        for (int c = 0; c < BATCH; c += 64) {
            const int i = c + t;
            const bool f = (lab[i] == la) && (i != a);
            const unsigned long long m = __ballot(f);
            if (f) {
                const int off = __popcll(m & ((1ull << t) - 1ull));
                plist[cnt + off] = i;
            }
            cnt += __popcll(m);
        }
        if (t == 0) npos_s = cnt;
    }
    __syncthreads();

    const int npos = npos_s;
    float sum = 0.f;
    int   pos = 0, valid = 0;

    for (int n = t; n < BATCH; n += 256) {
        if (lab[n] != la) {
            const float dan = drow[n];
            valid += npos;
            for (int q = 0; q < npos; ++q) {
                float tl = drow[plist[q]] - dan + MARGIN_F;
                if (tl > EPS_F) { sum += tl; ++pos; }
            }
        }
    }

#pragma unroll
    for (int off = 32; off > 0; off >>= 1) {
        sum   += __shfl_down(sum, off);
        pos   += __shfl_down(pos, off);
        valid += __shfl_down(valid, off);
    }
    const int wave = t >> 6, lane = t & 63;
    if (lane == 0) { ssum[wave] = sum; spos[wave] = pos; sval[wave] = valid; }
    __syncthreads();

    if (t == 0) {
        float s = 0.f; int p2 = 0, v = 0;
#pragma unroll
        for (int w = 0; w < 4; ++w) { s += ssum[w]; p2 += spos[w]; v += sval[w]; }
        part[a]             = s;
        part[BATCH + a]     = (float)p2;
        part[2 * BATCH + a] = (float)v;
    }
}

// ---------------------------------------------------------------------------
// Kernel 3: one-wave finalize (verbatim).
// ---------------------------------------------------------------------------
__global__ __launch_bounds__(64) void finalize_kernel(const float* __restrict__ part,
                                                      float* __restrict__ out) {
    const int lane = threadIdx.x;
    double s = 0.0, p = 0.0, v = 0.0;
#pragma unroll
    for (int c = 0; c < BATCH; c += 64) {
        s += (double)part[c + lane];
        p += (double)part[BATCH + c + lane];
        v += (double)part[2 * BATCH + c + lane];
    }
#pragma unroll
    for (int off = 32; off > 0; off >>= 1) {
        s += __shfl_down(s, off);
        p += __shfl_down(p, off);
        v += __shfl_down(v, off);
    }
    if (lane == 0) {
        out[0] = (float)(s / (p + 1e-16));
        out[1] = (float)p;
        out[2] = (float)v;
    }
}

extern "C" void kernel_launch(void* const* d_in, const int* in_sizes, int n_in,
                              void* d_out, int out_size, void* d_ws, size_t ws_size,
                              hipStream_t stream) {
    const int*   labels = (const int*)d_in[0];
    const float* E      = (const float*)d_in[1];
    float* out = (float*)d_out;

    // ws layout: [part @0: 3*384 f][ddiag @8192: 4*384 f][dpart @24576: 4*N2 f]
    float* part  = (float*)d_ws;
    float* ddiag = (float*)((char*)d_ws + 8192);
    float* dpart = (float*)((char*)d_ws + 24576);

    dist_kernel<<<DIST_BLKS, 256, 0, stream>>>(E, dpart, ddiag);
    triplet_kernel<<<BATCH, 256, 0, stream>>>(dpart, ddiag, labels, part);
    finalize_kernel<<<1, 64, 0, stream>>>(part, out);
}